// Round 18
// baseline (140.966 us; speedup 1.0000x reference)
//
#include <hip/hip_runtime.h>

// B=2, SQ=SKV=2048, D=1024, H=16, HD=64. Inputs fp32, output fp32.
// r17: KV-split attn gained 2.4us but combine pass cost ~6 -> net worse. Revert.
// r18: attn = r16 exactly (55us proven). GEMM body -> attn-style DOUBLE-BUFFERED
// staging with counted vmcnt (stage t+1 before compute t; vmcnt(8/6), never 0
// mid-loop). Same tiles/accum order -> bit-identical numerics.
#define DIM   1024
#define NHEAD 16
#define HDIM  64
#define BATCH 2
#define SEQ   2048
#define MTOT  4096   // B*SQ

typedef unsigned short u16;
typedef unsigned int   u32;
typedef __attribute__((ext_vector_type(8))) short bf16x8;   // 8 bf16 = 4 VGPRs
typedef __attribute__((ext_vector_type(4))) float f32x4;
typedef __attribute__((ext_vector_type(4))) u32   u32x4;

#define QSCALE 0.18033688011112042f   // 0.125 * log2(e)
#define EXP2F(x) __builtin_amdgcn_exp2f(x)
#define SWAP32(a, b) asm volatile("v_permlane32_swap_b32 %0, %1" : "+v"(a), "+v"(b))
#define SWAP16(a, b) asm volatile("v_permlane16_swap_b32 %0, %1" : "+v"(a), "+v"(b))

__device__ __forceinline__ void gload_lds16(const void* g, void* l) {
  __builtin_amdgcn_global_load_lds((const __attribute__((address_space(1))) void*)g,
                                   (__attribute__((address_space(3))) void*)l, 16, 0, 0);
}

__device__ __forceinline__ u16 f32_to_bf16(float f) {
  union { float f; u32 u; } v; v.f = f;
  u32 r = v.u + 0x7fffu + ((v.u >> 16) & 1u);   // RNE (v_cvt_pk_bf16_f32 is NOT RNE - r12)
  return (u16)(r >> 16);
}

__device__ __forceinline__ u32 pack_bf16(float a, float b) {
  return (u32)f32_to_bf16(a) | ((u32)f32_to_bf16(b) << 16);
}

// ---------------------------------------------------------------------------
// fp32 -> bf16 for all 7 tensors (3 inputs + 4 weights), manual RNE.
// ---------------------------------------------------------------------------
struct CvtArgs {
  const float* s[7];
  u16*         d[7];
  int          n8[7];
};

__global__ __launch_bounds__(256) void cvt_all(CvtArgs a) {
  const int z = blockIdx.z;
  const float* s = a.s[z];
  u16* d = a.d[z];
  const int n8 = a.n8[z];
  const int stride = gridDim.x * blockDim.x;
  for (int i = blockIdx.x * blockDim.x + threadIdx.x; i < n8; i += stride) {
    float4 x = ((const float4*)s)[2 * i], y = ((const float4*)s)[2 * i + 1];
    u32x4 o;
    o[0] = pack_bf16(x.x, x.y); o[1] = pack_bf16(x.z, x.w);
    o[2] = pack_bf16(y.x, y.y); o[3] = pack_bf16(y.z, y.w);
    *(u32x4*)&d[(size_t)i * 8] = o;
  }
}

// ---------------------------------------------------------------------------
// bf16 GEMM body, DOUBLE-BUFFERED: tile (32*MF) x 128, BK=64, 4 waves (2x2).
// Stage K-step t+1 while computing t; counted vmcnt (8 for MF=4, 6 for MF=2),
// raw s_barrier. gload_lds + both-sides XOR swizzle (proven r7-r17).
// ---------------------------------------------------------------------------
template<int MF, bool OUTF32, bool BIAS_ROW>
__device__ __forceinline__ void gemm_body(
    const u16* __restrict__ X, const u16* __restrict__ W,
    const float* __restrict__ bias, void* __restrict__ Cv, int ldc, float scale,
    int m0, int n0)
{
  __shared__ __align__(16) u16 ldsA[2][MF * 32 * 64];
  __shared__ __align__(16) u16 ldsB[2][128 * 64];
  const int tid  = threadIdx.x;
  const int lane = tid & 63;
  const int wid  = tid >> 6;
  const int wr   = wid >> 1, wc = wid & 1;
  const int srow = tid >> 3;
  const int scs  = tid & 7;

  f32x4 acc[MF][4];
#pragma unroll
  for (int mf = 0; mf < MF; ++mf)
#pragma unroll
    for (int nf = 0; nf < 4; ++nf)
#pragma unroll
      for (int r = 0; r < 4; ++r) acc[mf][nf][r] = 0.f;

#define GSTAGE(TI, BUF)                                                        \
  {                                                                            \
    const int kt = (TI) * 64;                                                  \
    _Pragma("unroll")                                                          \
    for (int call = 0; call < MF; ++call) {                                    \
      int row = call * 32 + srow;                                              \
      int lc  = scs ^ (row & 7);                                               \
      gload_lds16(X + (size_t)(m0 + row) * DIM + kt + lc * 8,                  \
                  &ldsA[BUF][(row * 8 + scs) * 8]);                            \
    }                                                                          \
    _Pragma("unroll")                                                          \
    for (int call = 0; call < 4; ++call) {                                     \
      int row = call * 32 + srow;                                              \
      int lc  = scs ^ (row & 7);                                               \
      gload_lds16(W + (size_t)(n0 + row) * DIM + kt + lc * 8,                  \
                  &ldsB[BUF][(row * 8 + scs) * 8]);                            \
    }                                                                          \
  }

  GSTAGE(0, 0);

  for (int ti = 0; ti < 16; ++ti) {
    const int cur = ti & 1;
    if (ti < 15) {
      GSTAGE(ti + 1, cur ^ 1);
      if (MF == 4) asm volatile("s_waitcnt vmcnt(8)" ::: "memory");
      else         asm volatile("s_waitcnt vmcnt(6)" ::: "memory");
    } else {
      asm volatile("s_waitcnt vmcnt(0)" ::: "memory");
    }
    __builtin_amdgcn_sched_barrier(0);
    __builtin_amdgcn_s_barrier();          // buf[cur] staged & visible
    __builtin_amdgcn_sched_barrier(0);

#pragma unroll
    for (int ks = 0; ks < 2; ++ks) {
      bf16x8 af[MF], bfr[4];
#pragma unroll
      for (int mf = 0; mf < MF; ++mf) {
        int row = wr * (16 * MF) + mf * 16 + (lane & 15);
        int ch  = (ks * 4 + (lane >> 4)) ^ (row & 7);
        af[mf] = *(const bf16x8*)&ldsA[cur][row * 64 + ch * 8];
      }
#pragma unroll
      for (int nf = 0; nf < 4; ++nf) {
        int row = wc * 64 + nf * 16 + (lane & 15);
        int ch  = (ks * 4 + (lane >> 4)) ^ (row & 7);
        bfr[nf] = *(const bf16x8*)&ldsB[cur][row * 64 + ch * 8];
      }
#pragma unroll
      for (int mf = 0; mf < MF; ++mf)
#pragma unroll
        for (int nf = 0; nf < 4; ++nf)
          acc[mf][nf] = __builtin_amdgcn_mfma_f32_16x16x32_bf16(
              af[mf], bfr[nf], acc[mf][nf], 0, 0, 0);
    }

    __builtin_amdgcn_sched_barrier(0);
    __builtin_amdgcn_s_barrier();          // all waves done with buf[cur]
  }
#undef GSTAGE

#pragma unroll
  for (int nf = 0; nf < 4; ++nf) {
    int col = n0 + wc * 64 + nf * 16 + (lane & 15);
    float bcol = BIAS_ROW ? 0.f : bias[col];
#pragma unroll
    for (int mf = 0; mf < MF; ++mf) {
      int rbase = m0 + wr * (16 * MF) + mf * 16 + ((lane >> 4) << 2);
#pragma unroll
      for (int r = 0; r < 4; ++r) {
        float bv = BIAS_ROW ? bias[rbase + r] : bcol;
        float v = (acc[mf][nf][r] + bv) * scale;
        if (OUTF32) ((float*)Cv)[(size_t)(rbase + r) * ldc + col] = v;
        else        ((u16*)Cv)[(size_t)(rbase + r) * ldc + col] = f32_to_bf16(v);
      }
    }
  }
}

// Fused projections, 1D grid 768, XCD-chunked: z=0 Q, z=1 K, z=2 V^T.
__global__ __launch_bounds__(256, 2) void gemm_proj_kernel(
    const u16* __restrict__ q, const u16* __restrict__ k, const u16* __restrict__ v,
    const u16* __restrict__ wq, const u16* __restrict__ wk, const u16* __restrict__ wv,
    const float* __restrict__ bq, const float* __restrict__ bk, const float* __restrict__ bv,
    u16* __restrict__ oq, u16* __restrict__ ok, u16* __restrict__ ovt)
{
  const int bid = blockIdx.x;
  const int wk_ = (bid & 7) * 96 + (bid >> 3);   // 768 = 8 XCD x 96, bijective
  const int z = wk_ >> 8, rem = wk_ & 255;
  const int ty = rem >> 3, tx = rem & 7;
  if (z == 0)
    gemm_body<4, false, false>(q, wq, bq, oq, DIM, QSCALE, ty * 128, tx * 128);
  else if (z == 1)
    gemm_body<4, false, false>(k, wk, bk, ok, DIM, 1.0f, ty * 128, tx * 128);
  else
    gemm_body<4, false, true>(wv, v, bv, ovt, MTOT, 1.0f, tx * 128, ty * 128);
}

// O projection: 64x128 tile, 1D grid 512, XCD-chunked.
__global__ __launch_bounds__(256, 2) void gemm_o_kernel(
    const u16* __restrict__ x, const u16* __restrict__ w,
    const float* __restrict__ b, float* __restrict__ c)
{
  const int bid = blockIdx.x;
  const int wk_ = (bid & 7) * 64 + (bid >> 3);   // 512 = 8 x 64, bijective
  const int ty = wk_ >> 3, tx = wk_ & 7;
  gemm_body<2, true, false>(x, w, b, c, DIM, 1.0f, ty * 64, tx * 128);
}

// ---------------------------------------------------------------------------
// Flash attention (r16, proven 55us): 512 blk, 4 waves x 32 q, KVBLK=128.
// Swapped QK^T streamed per nvk -> exp2 -> packed W[8][2][2] -> permlane PV.
// ---------------------------------------------------------------------------
__global__ __launch_bounds__(256, 2) void attn_kernel(
    const u16* __restrict__ Qm, const u16* __restrict__ Km,
    const u16* __restrict__ Vt, u16* __restrict__ Cm)
{
  __shared__ __align__(16) u16 Kl[2][128 * 64];
  __shared__ __align__(16) u16 Vl[2][64 * 128];

  const int tid = threadIdx.x, lane = tid & 63, wid = tid >> 6;
  const int c = lane & 15, g = lane >> 4;
  const int wkid = (blockIdx.x & 7) * 64 + (blockIdx.x >> 3);   // XCD-chunked
  const int qt = wkid & 15;
  const int bh = wkid >> 4;
  const int b = bh >> 4, h = bh & 15;
  const size_t hb = (size_t)h * HDIM;
  const int q0 = qt * 128 + wid * 32;
  const u16* Qh = Qm + ((size_t)b * SEQ + q0) * DIM + hb;
  const u16* Kh = Km + (size_t)b * SEQ * DIM + hb;
  const u16* Vh = Vt + (size_t)(h * HDIM) * MTOT + (size_t)b * SEQ;

  bf16x8 qf[2][2];
#pragma unroll
  for (int mf = 0; mf < 2; ++mf)
#pragma unroll
    for (int ks = 0; ks < 2; ++ks)
      qf[mf][ks] = *(const bf16x8*)(Qh + (size_t)(16 * mf + c) * DIM + ks * 32 + g * 8);

  bf16x8 ones;
#pragma unroll
  for (int j = 0; j < 8; ++j) ((short*)&ones)[j] = (short)0x3F80;   // bf16 1.0

  f32x4 oacc[2][4], lacc[2];
#pragma unroll
  for (int mf = 0; mf < 2; ++mf) {
#pragma unroll
    for (int nd = 0; nd < 4; ++nd)
#pragma unroll
      for (int r = 0; r < 4; ++r) oacc[mf][nd][r] = 0.f;
#pragma unroll
    for (int r = 0; r < 4; ++r) lacc[mf][r] = 0.f;
  }

  const int srow = tid >> 3, scs = tid & 7;      // K staging (8 chunks/row)
  const int srow2 = tid >> 4, scs2 = tid & 15;   // V staging (16 chunks/row)

#define STAGE(T, BUF)                                                          \
  {                                                                            \
    const int kvs = (T) * 128;                                                 \
    _Pragma("unroll")                                                          \
    for (int call = 0; call < 4; ++call) {                                     \
      int row = call * 32 + srow;                                              \
      int lc  = scs ^ (row & 7);                                               \
      gload_lds16(Kh + (size_t)(kvs + row) * DIM + lc * 8,                     \
                  &Kl[BUF][(row * 8 + scs) * 8]);                              \
    }                                                                          \
    _Pragma("unroll")                                                          \
    for (int call = 0; call < 4; ++call) {                                     \
      int row = call * 16 + srow2;                                             \
      int lc  = scs2 ^ (row & 15);                                             \
      gload_lds16(Vh + (size_t)row * MTOT + kvs + lc * 8,                      \
                  &Vl[BUF][(row * 16 + scs2) * 8]);                            \
    }                                                                          \
  }

  STAGE(0, 0);

  for (int t = 0; t < 16; ++t) {
    const int cur = t & 1;
    if (t < 15) {
      STAGE(t + 1, cur ^ 1);
      asm volatile("s_waitcnt vmcnt(8)" ::: "memory");
    } else {
      asm volatile("s_waitcnt vmcnt(0)" ::: "memory");
    }
    __builtin_amdgcn_sched_barrier(0);
    __builtin_amdgcn_s_barrier();          // buf[cur] staged & visible
    __builtin_amdgcn_sched_barrier(0);
    __builtin_amdgcn_s_setprio(1);

    // ---- QK^T swapped, streamed per nvk: P[kv=16nvk+4g+r][q=16mf+c] ----
    u32 W[8][2][2];
#pragma unroll
    for (int nvk = 0; nvk < 8; ++nvk) {
      int row = nvk * 16 + c;              // kv row in 128-tile
      f32x4 sacc[2];
#pragma unroll
      for (int mf = 0; mf < 2; ++mf)
#pragma unroll
        for (int r = 0; r < 4; ++r) sacc[mf][r] = 0.f;
#pragma unroll
      for (int ks = 0; ks < 2; ++ks) {
        int ch = (ks * 4 + g) ^ (row & 7);
        bf16x8 kf = *(const bf16x8*)&Kl[cur][row * 64 + ch * 8];
#pragma unroll
        for (int mf = 0; mf < 2; ++mf)
          sacc[mf] = __builtin_amdgcn_mfma_f32_16x16x32_bf16(
              kf, qf[mf][ks], sacc[mf], 0, 0, 0);
      }
#pragma unroll
      for (int mf = 0; mf < 2; ++mf) {
        W[nvk][mf][0] = pack_bf16(EXP2F(sacc[mf][0]), EXP2F(sacc[mf][1]));
        W[nvk][mf][1] = pack_bf16(EXP2F(sacc[mf][2]), EXP2F(sacc[mf][3]));
      }
    }

    // ---- PV with in-register P: ks 0..3 over kv=128 ----
#pragma unroll
    for (int ks = 0; ks < 4; ++ks) {
      bf16x8 vfr[4];
#pragma unroll
      for (int nd = 0; nd < 4; ++nd) {
        int row = nd * 16 + c;             // d row of V^T tile
        int ch  = (ks * 4 + g) ^ (row & 15);
        vfr[nd] = *(const bf16x8*)&Vl[cur][row * 128 + ch * 8];
      }
#pragma unroll
      for (int mf = 0; mf < 2; ++mf) {
        u32 a0 = W[2 * ks][mf][0], b0 = W[2 * ks + 1][mf][0];
        u32 a1 = W[2 * ks][mf][1], b1 = W[2 * ks + 1][mf][1];
        SWAP32(a0, b0); SWAP16(a0, b0);
        SWAP32(a1, b1); SWAP16(a1, b1);
        u32x4 pw4; pw4[0] = a0; pw4[1] = a1; pw4[2] = b0; pw4[3] = b1;
        bf16x8 pa = __builtin_bit_cast(bf16x8, pw4);
        lacc[mf] = __builtin_amdgcn_mfma_f32_16x16x32_bf16(
            pa, ones, lacc[mf], 0, 0, 0);
#pragma unroll
        for (int nd = 0; nd < 4; ++nd)
          oacc[mf][nd] = __builtin_amdgcn_mfma_f32_16x16x32_bf16(
              pa, vfr[nd], oacc[mf][nd], 0, 0, 0);
      }
    }

    __builtin_amdgcn_s_setprio(0);
    __builtin_amdgcn_sched_barrier(0);
    __builtin_amdgcn_s_barrier();          // all waves done with buf[cur]
  }
#undef STAGE

  // epilogue: q = q0 + 16mf + 4g + r, d = 16nd + c
#pragma unroll
  for (int mf = 0; mf < 2; ++mf)
#pragma unroll
    for (int nd = 0; nd < 4; ++nd)
#pragma unroll
      for (int r = 0; r < 4; ++r) {
        int q = q0 + 16 * mf + 4 * g + r;
        float v = oacc[mf][nd][r] / lacc[mf][r];
        Cm[((size_t)b * SEQ + q) * DIM + hb + nd * 16 + c] = f32_to_bf16(v);
      }
}

// ---------------------------------------------------------------------------
extern "C" void kernel_launch(void* const* d_in, const int* in_sizes, int n_in,
                              void* d_out, int out_size, void* d_ws, size_t ws_size,
                              hipStream_t stream)
{
  const float* query = (const float*)d_in[0];
  const float* key   = (const float*)d_in[1];
  const float* value = (const float*)d_in[2];
  const float* Wq = (const float*)d_in[3];  const float* bq = (const float*)d_in[4];
  const float* Wk = (const float*)d_in[5];  const float* bk = (const float*)d_in[6];
  const float* Wv = (const float*)d_in[7];  const float* bv = (const float*)d_in[8];
  const float* Wo = (const float*)d_in[9];  const float* bo = (const float*)d_in[10];
  float* out = (float*)d_out;

  const size_t NQKV = (size_t)MTOT * DIM;
  const size_t NW   = (size_t)DIM * DIM;
  u16* base = (u16*)d_ws;
  u16* Qb  = base;                 // [4096,1024] (pre-scaled by QSCALE)
  u16* Kb  = Qb + NQKV;
  u16* Vtb = Kb + NQKV;            // [1024,4096] V^T
  u16* Cb  = Vtb + NQKV;
  u16* qc  = Cb + NQKV;
  u16* kc  = qc + NQKV;
  u16* vc  = kc + NQKV;
  u16* wqc = vc + NQKV;
  u16* wkc = wqc + NW;
  u16* wvc = wkc + NW;
  u16* woc = wvc + NW;

  CvtArgs ca;
  ca.s[0] = query; ca.s[1] = key; ca.s[2] = value;
  ca.s[3] = Wq; ca.s[4] = Wk; ca.s[5] = Wv; ca.s[6] = Wo;
  ca.d[0] = qc; ca.d[1] = kc; ca.d[2] = vc;
  ca.d[3] = wqc; ca.d[4] = wkc; ca.d[5] = wvc; ca.d[6] = woc;
  for (int i = 0; i < 3; ++i) ca.n8[i] = (int)(NQKV / 8);
  for (int i = 3; i < 7; ++i) ca.n8[i] = (int)(NW / 8);
  cvt_all<<<dim3(256, 1, 7), 256, 0, stream>>>(ca);

  dim3 blk(256);
  gemm_proj_kernel<<<768, blk, 0, stream>>>(
      qc, kc, vc, wqc, wkc, wvc, bq, bk, bv, Qb, Kb, Vtb);
  attn_kernel<<<512, blk, 0, stream>>>(Qb, Kb, Vtb, Cb);
  gemm_o_kernel<<<512, blk, 0, stream>>>(Cb, woc, bo, out);
}

// Round 19
// 114.028 us; speedup vs baseline: 1.2362x; 1.2362x over previous
//
#include <hip/hip_runtime.h>

// B=2, SQ=SKV=2048, D=1024, H=16, HD=64. Inputs fp32, output fp32.
// r18: GEMM dbuf regressed (128KB LDS -> 1 blk/CU, proj 30->62us; m132 lesson
// reproduced). r19: GEMM reverted to r16 single-buffered (proven). attn: P
// packing RNE->TRUNC (3 ops vs ~10; bias cancels in O/ell ratio since both
// use the same rounded P). Everything else = r16 (120.9us baseline).
#define DIM   1024
#define NHEAD 16
#define HDIM  64
#define BATCH 2
#define SEQ   2048
#define MTOT  4096   // B*SQ

typedef unsigned short u16;
typedef unsigned int   u32;
typedef __attribute__((ext_vector_type(8))) short bf16x8;   // 8 bf16 = 4 VGPRs
typedef __attribute__((ext_vector_type(4))) float f32x4;
typedef __attribute__((ext_vector_type(4))) u32   u32x4;

#define QSCALE 0.18033688011112042f   // 0.125 * log2(e)
#define EXP2F(x) __builtin_amdgcn_exp2f(x)
#define SWAP32(a, b) asm volatile("v_permlane32_swap_b32 %0, %1" : "+v"(a), "+v"(b))
#define SWAP16(a, b) asm volatile("v_permlane16_swap_b32 %0, %1" : "+v"(a), "+v"(b))

__device__ __forceinline__ void gload_lds16(const void* g, void* l) {
  __builtin_amdgcn_global_load_lds((const __attribute__((address_space(1))) void*)g,
                                   (__attribute__((address_space(3))) void*)l, 16, 0, 0);
}

__device__ __forceinline__ u16 f32_to_bf16(float f) {
  union { float f; u32 u; } v; v.f = f;
  u32 r = v.u + 0x7fffu + ((v.u >> 16) & 1u);   // RNE (v_cvt_pk_bf16_f32 is NOT RNE - r12)
  return (u16)(r >> 16);
}

__device__ __forceinline__ u32 pack_bf16(float a, float b) {
  return (u32)f32_to_bf16(a) | ((u32)f32_to_bf16(b) << 16);
}

// Truncation pack for P only: numerator and denominator share the same
// truncated P, so the bias cancels in O/ell; ~3 VALU ops vs ~10 for RNE.
__device__ __forceinline__ u32 pack_bf16_trunc(float a, float b) {
  u32 ua = __builtin_bit_cast(u32, a), ub = __builtin_bit_cast(u32, b);
  return (ua >> 16) | (ub & 0xFFFF0000u);
}

// ---------------------------------------------------------------------------
// fp32 -> bf16 for all 7 tensors (3 inputs + 4 weights), manual RNE.
// ---------------------------------------------------------------------------
struct CvtArgs {
  const float* s[7];
  u16*         d[7];
  int          n8[7];
};

__global__ __launch_bounds__(256) void cvt_all(CvtArgs a) {
  const int z = blockIdx.z;
  const float* s = a.s[z];
  u16* d = a.d[z];
  const int n8 = a.n8[z];
  const int stride = gridDim.x * blockDim.x;
  for (int i = blockIdx.x * blockDim.x + threadIdx.x; i < n8; i += stride) {
    float4 x = ((const float4*)s)[2 * i], y = ((const float4*)s)[2 * i + 1];
    u32x4 o;
    o[0] = pack_bf16(x.x, x.y); o[1] = pack_bf16(x.z, x.w);
    o[2] = pack_bf16(y.x, y.y); o[3] = pack_bf16(y.z, y.w);
    *(u32x4*)&d[(size_t)i * 8] = o;
  }
}

// ---------------------------------------------------------------------------
// bf16 GEMM body (r16-proven, single-buffered): tile (32*MF) x 128, BK=64,
// 4 waves (2x2), all-gload_lds staging + both-sides XOR swizzle.
// ---------------------------------------------------------------------------
template<int MF, bool OUTF32, bool BIAS_ROW>
__device__ __forceinline__ void gemm_body(
    const u16* __restrict__ X, const u16* __restrict__ W,
    const float* __restrict__ bias, void* __restrict__ Cv, int ldc, float scale,
    int m0, int n0)
{
  __shared__ __align__(16) u16 ldsA[32 * 4 * 64];
  __shared__ __align__(16) u16 ldsB[128 * 64];
  const int tid  = threadIdx.x;
  const int lane = tid & 63;
  const int wid  = tid >> 6;
  const int wr   = wid >> 1, wc = wid & 1;
  const int srow = tid >> 3;
  const int scs  = tid & 7;

  f32x4 acc[MF][4];
#pragma unroll
  for (int mf = 0; mf < MF; ++mf)
#pragma unroll
    for (int nf = 0; nf < 4; ++nf)
#pragma unroll
      for (int r = 0; r < 4; ++r) acc[mf][nf][r] = 0.f;

  for (int kt = 0; kt < DIM; kt += 64) {
    __syncthreads();
#pragma unroll
    for (int call = 0; call < MF; ++call) {
      int row = call * 32 + srow;
      int lc  = scs ^ (row & 7);
      gload_lds16(X + (size_t)(m0 + row) * DIM + kt + lc * 8,
                  &ldsA[(row * 8 + scs) * 8]);
    }
#pragma unroll
    for (int call = 0; call < 4; ++call) {
      int row = call * 32 + srow;
      int lc  = scs ^ (row & 7);
      gload_lds16(W + (size_t)(n0 + row) * DIM + kt + lc * 8,
                  &ldsB[(row * 8 + scs) * 8]);
    }
    __syncthreads();
#pragma unroll
    for (int ks = 0; ks < 2; ++ks) {
      bf16x8 af[MF], bfr[4];
#pragma unroll
      for (int mf = 0; mf < MF; ++mf) {
        int row = wr * (16 * MF) + mf * 16 + (lane & 15);
        int ch  = (ks * 4 + (lane >> 4)) ^ (row & 7);
        af[mf] = *(const bf16x8*)&ldsA[row * 64 + ch * 8];
      }
#pragma unroll
      for (int nf = 0; nf < 4; ++nf) {
        int row = wc * 64 + nf * 16 + (lane & 15);
        int ch  = (ks * 4 + (lane >> 4)) ^ (row & 7);
        bfr[nf] = *(const bf16x8*)&ldsB[row * 64 + ch * 8];
      }
#pragma unroll
      for (int mf = 0; mf < MF; ++mf)
#pragma unroll
        for (int nf = 0; nf < 4; ++nf)
          acc[mf][nf] = __builtin_amdgcn_mfma_f32_16x16x32_bf16(
              af[mf], bfr[nf], acc[mf][nf], 0, 0, 0);
    }
  }
#pragma unroll
  for (int nf = 0; nf < 4; ++nf) {
    int col = n0 + wc * 64 + nf * 16 + (lane & 15);
    float bcol = BIAS_ROW ? 0.f : bias[col];
#pragma unroll
    for (int mf = 0; mf < MF; ++mf) {
      int rbase = m0 + wr * (16 * MF) + mf * 16 + ((lane >> 4) << 2);
#pragma unroll
      for (int r = 0; r < 4; ++r) {
        float bv = BIAS_ROW ? bias[rbase + r] : bcol;
        float v = (acc[mf][nf][r] + bv) * scale;
        if (OUTF32) ((float*)Cv)[(size_t)(rbase + r) * ldc + col] = v;
        else        ((u16*)Cv)[(size_t)(rbase + r) * ldc + col] = f32_to_bf16(v);
      }
    }
  }
}

// Fused projections, 1D grid 768, XCD-chunked: z=0 Q, z=1 K, z=2 V^T.
__global__ __launch_bounds__(256, 2) void gemm_proj_kernel(
    const u16* __restrict__ q, const u16* __restrict__ k, const u16* __restrict__ v,
    const u16* __restrict__ wq, const u16* __restrict__ wk, const u16* __restrict__ wv,
    const float* __restrict__ bq, const float* __restrict__ bk, const float* __restrict__ bv,
    u16* __restrict__ oq, u16* __restrict__ ok, u16* __restrict__ ovt)
{
  const int bid = blockIdx.x;
  const int wk_ = (bid & 7) * 96 + (bid >> 3);   // 768 = 8 XCD x 96, bijective
  const int z = wk_ >> 8, rem = wk_ & 255;
  const int ty = rem >> 3, tx = rem & 7;
  if (z == 0)
    gemm_body<4, false, false>(q, wq, bq, oq, DIM, QSCALE, ty * 128, tx * 128);
  else if (z == 1)
    gemm_body<4, false, false>(k, wk, bk, ok, DIM, 1.0f, ty * 128, tx * 128);
  else
    gemm_body<4, false, true>(wv, v, bv, ovt, MTOT, 1.0f, tx * 128, ty * 128);
}

// O projection: 64x128 tile, 1D grid 512, XCD-chunked.
__global__ __launch_bounds__(256, 2) void gemm_o_kernel(
    const u16* __restrict__ x, const u16* __restrict__ w,
    const float* __restrict__ b, float* __restrict__ c)
{
  const int bid = blockIdx.x;
  const int wk_ = (bid & 7) * 64 + (bid >> 3);   // 512 = 8 x 64, bijective
  const int ty = wk_ >> 3, tx = wk_ & 7;
  gemm_body<2, true, false>(x, w, b, c, DIM, 1.0f, ty * 64, tx * 128);
}

// ---------------------------------------------------------------------------
// Flash attention (r16 structure, 55us): 512 blk, 4 waves x 32 q, KVBLK=128.
// Swapped QK^T streamed per nvk -> exp2 -> TRUNC-packed W[8][2][2] -> permlane
// PV (P never in LDS). setprio(1) around compute.
// ---------------------------------------------------------------------------
__global__ __launch_bounds__(256, 2) void attn_kernel(
    const u16* __restrict__ Qm, const u16* __restrict__ Km,
    const u16* __restrict__ Vt, u16* __restrict__ Cm)
{
  __shared__ __align__(16) u16 Kl[2][128 * 64];
  __shared__ __align__(16) u16 Vl[2][64 * 128];

  const int tid = threadIdx.x, lane = tid & 63, wid = tid >> 6;
  const int c = lane & 15, g = lane >> 4;
  const int wkid = (blockIdx.x & 7) * 64 + (blockIdx.x >> 3);   // XCD-chunked
  const int qt = wkid & 15;
  const int bh = wkid >> 4;
  const int b = bh >> 4, h = bh & 15;
  const size_t hb = (size_t)h * HDIM;
  const int q0 = qt * 128 + wid * 32;
  const u16* Qh = Qm + ((size_t)b * SEQ + q0) * DIM + hb;
  const u16* Kh = Km + (size_t)b * SEQ * DIM + hb;
  const u16* Vh = Vt + (size_t)(h * HDIM) * MTOT + (size_t)b * SEQ;

  bf16x8 qf[2][2];
#pragma unroll
  for (int mf = 0; mf < 2; ++mf)
#pragma unroll
    for (int ks = 0; ks < 2; ++ks)
      qf[mf][ks] = *(const bf16x8*)(Qh + (size_t)(16 * mf + c) * DIM + ks * 32 + g * 8);

  bf16x8 ones;
#pragma unroll
  for (int j = 0; j < 8; ++j) ((short*)&ones)[j] = (short)0x3F80;   // bf16 1.0

  f32x4 oacc[2][4], lacc[2];
#pragma unroll
  for (int mf = 0; mf < 2; ++mf) {
#pragma unroll
    for (int nd = 0; nd < 4; ++nd)
#pragma unroll
      for (int r = 0; r < 4; ++r) oacc[mf][nd][r] = 0.f;
#pragma unroll
    for (int r = 0; r < 4; ++r) lacc[mf][r] = 0.f;
  }

  const int srow = tid >> 3, scs = tid & 7;      // K staging (8 chunks/row)
  const int srow2 = tid >> 4, scs2 = tid & 15;   // V staging (16 chunks/row)

#define STAGE(T, BUF)                                                          \
  {                                                                            \
    const int kvs = (T) * 128;                                                 \
    _Pragma("unroll")                                                          \
    for (int call = 0; call < 4; ++call) {                                     \
      int row = call * 32 + srow;                                              \
      int lc  = scs ^ (row & 7);                                               \
      gload_lds16(Kh + (size_t)(kvs + row) * DIM + lc * 8,                     \
                  &Kl[BUF][(row * 8 + scs) * 8]);                              \
    }                                                                          \
    _Pragma("unroll")                                                          \
    for (int call = 0; call < 4; ++call) {                                     \
      int row = call * 16 + srow2;                                             \
      int lc  = scs2 ^ (row & 15);                                             \
      gload_lds16(Vh + (size_t)row * MTOT + kvs + lc * 8,                      \
                  &Vl[BUF][(row * 16 + scs2) * 8]);                            \
    }                                                                          \
  }

  STAGE(0, 0);

  for (int t = 0; t < 16; ++t) {
    const int cur = t & 1;
    if (t < 15) {
      STAGE(t + 1, cur ^ 1);
      asm volatile("s_waitcnt vmcnt(8)" ::: "memory");
    } else {
      asm volatile("s_waitcnt vmcnt(0)" ::: "memory");
    }
    __builtin_amdgcn_sched_barrier(0);
    __builtin_amdgcn_s_barrier();          // buf[cur] staged & visible
    __builtin_amdgcn_sched_barrier(0);
    __builtin_amdgcn_s_setprio(1);

    // ---- QK^T swapped, streamed per nvk: P[kv=16nvk+4g+r][q=16mf+c] ----
    u32 W[8][2][2];
#pragma unroll
    for (int nvk = 0; nvk < 8; ++nvk) {
      int row = nvk * 16 + c;              // kv row in 128-tile
      f32x4 sacc[2];
#pragma unroll
      for (int mf = 0; mf < 2; ++mf)
#pragma unroll
        for (int r = 0; r < 4; ++r) sacc[mf][r] = 0.f;
#pragma unroll
      for (int ks = 0; ks < 2; ++ks) {
        int ch = (ks * 4 + g) ^ (row & 7);
        bf16x8 kf = *(const bf16x8*)&Kl[cur][row * 64 + ch * 8];
#pragma unroll
        for (int mf = 0; mf < 2; ++mf)
          sacc[mf] = __builtin_amdgcn_mfma_f32_16x16x32_bf16(
              kf, qf[mf][ks], sacc[mf], 0, 0, 0);
      }
#pragma unroll
      for (int mf = 0; mf < 2; ++mf) {
        W[nvk][mf][0] = pack_bf16_trunc(EXP2F(sacc[mf][0]), EXP2F(sacc[mf][1]));
        W[nvk][mf][1] = pack_bf16_trunc(EXP2F(sacc[mf][2]), EXP2F(sacc[mf][3]));
      }
    }

    // ---- PV with in-register P: ks 0..3 over kv=128 ----
#pragma unroll
    for (int ks = 0; ks < 4; ++ks) {
      bf16x8 vfr[4];
#pragma unroll
      for (int nd = 0; nd < 4; ++nd) {
        int row = nd * 16 + c;             // d row of V^T tile
        int ch  = (ks * 4 + g) ^ (row & 15);
        vfr[nd] = *(const bf16x8*)&Vl[cur][row * 128 + ch * 8];
      }
#pragma unroll
      for (int mf = 0; mf < 2; ++mf) {
        u32 a0 = W[2 * ks][mf][0], b0 = W[2 * ks + 1][mf][0];
        u32 a1 = W[2 * ks][mf][1], b1 = W[2 * ks + 1][mf][1];
        SWAP32(a0, b0); SWAP16(a0, b0);
        SWAP32(a1, b1); SWAP16(a1, b1);
        u32x4 pw4; pw4[0] = a0; pw4[1] = a1; pw4[2] = b0; pw4[3] = b1;
        bf16x8 pa = __builtin_bit_cast(bf16x8, pw4);
        lacc[mf] = __builtin_amdgcn_mfma_f32_16x16x32_bf16(
            pa, ones, lacc[mf], 0, 0, 0);
#pragma unroll
        for (int nd = 0; nd < 4; ++nd)
          oacc[mf][nd] = __builtin_amdgcn_mfma_f32_16x16x32_bf16(
              pa, vfr[nd], oacc[mf][nd], 0, 0, 0);
      }
    }

    __builtin_amdgcn_s_setprio(0);
    __builtin_amdgcn_sched_barrier(0);
    __builtin_amdgcn_s_barrier();          // all waves done with buf[cur]
  }
#undef STAGE

  // epilogue: q = q0 + 16mf + 4g + r, d = 16nd + c
#pragma unroll
  for (int mf = 0; mf < 2; ++mf)
#pragma unroll
    for (int nd = 0; nd < 4; ++nd)
#pragma unroll
      for (int r = 0; r < 4; ++r) {
        int q = q0 + 16 * mf + 4 * g + r;
        float v = oacc[mf][nd][r] / lacc[mf][r];
        Cm[((size_t)b * SEQ + q) * DIM + hb + nd * 16 + c] = f32_to_bf16(v);
      }
}

// ---------------------------------------------------------------------------
extern "C" void kernel_launch(void* const* d_in, const int* in_sizes, int n_in,
                              void* d_out, int out_size, void* d_ws, size_t ws_size,
                              hipStream_t stream)
{
  const float* query = (const float*)d_in[0];
  const float* key   = (const float*)d_in[1];
  const float* value = (const float*)d_in[2];
  const float* Wq = (const float*)d_in[3];  const float* bq = (const float*)d_in[4];
  const float* Wk = (const float*)d_in[5];  const float* bk = (const float*)d_in[6];
  const float* Wv = (const float*)d_in[7];  const float* bv = (const float*)d_in[8];
  const float* Wo = (const float*)d_in[9];  const float* bo = (const float*)d_in[10];
  float* out = (float*)d_out;

  const size_t NQKV = (size_t)MTOT * DIM;
  const size_t NW   = (size_t)DIM * DIM;
  u16* base = (u16*)d_ws;
  u16* Qb  = base;                 // [4096,1024] (pre-scaled by QSCALE)
  u16* Kb  = Qb + NQKV;
  u16* Vtb = Kb + NQKV;            // [1024,4096] V^T
  u16* Cb  = Vtb + NQKV;
  u16* qc  = Cb + NQKV;
  u16* kc  = qc + NQKV;
  u16* vc  = kc + NQKV;
  u16* wqc = vc + NQKV;
  u16* wkc = wqc + NW;
  u16* wvc = wkc + NW;
  u16* woc = wvc + NW;

  CvtArgs ca;
  ca.s[0] = query; ca.s[1] = key; ca.s[2] = value;
  ca.s[3] = Wq; ca.s[4] = Wk; ca.s[5] = Wv; ca.s[6] = Wo;
  ca.d[0] = qc; ca.d[1] = kc; ca.d[2] = vc;
  ca.d[3] = wqc; ca.d[4] = wkc; ca.d[5] = wvc; ca.d[6] = woc;
  for (int i = 0; i < 3; ++i) ca.n8[i] = (int)(NQKV / 8);
  for (int i = 3; i < 7; ++i) ca.n8[i] = (int)(NW / 8);
  cvt_all<<<dim3(256, 1, 7), 256, 0, stream>>>(ca);

  dim3 blk(256);
  gemm_proj_kernel<<<768, blk, 0, stream>>>(
      qc, kc, vc, wqc, wkc, wvc, bq, bk, bv, Qb, Kb, Vtb);
  attn_kernel<<<512, blk, 0, stream>>>(Qb, Kb, Vtb, Cb);
  gemm_o_kernel<<<512, blk, 0, stream>>>(Cb, woc, bo, out);
}